// Round 9
// baseline (263.745 us; speedup 1.0000x reference)
//
#include <hip/hip_runtime.h>

// DilatedAttention: b=2,h=16,s=8192,d=64; W=[4,8,16], R=[1,2,4] -> L=4 for all
// groups. Rows flatten to 262144 x 64; a 32-row span is self-contained. fp32.
//
// V10: TWO barrier-free streaming passes chained through d_ws (7.3 MB of
// weight-folded probs). Evidence from V1-V9: every fused structure pins at
// ~86-117 us with all pipes <40% busy; effective BW tracks TRAFFIC (spill
// raised BW 1.8->2.4 TB/s), i.e. the limiter is per-wave load duty cycle --
// loads burst briefly between dependent compute/barriers, then waves idle
// with zero outstanding misses. Fix: make both passes copy-kernel-shaped:
//   A (scores): grid-stride, no LDS, no barriers; 32 indep loads per item,
//     dot, 4-lane shfl softmax, store wg*p/sum. unroll-2 overlaps items.
//   B (PV): grid-stride, no LDS, no barriers; wave-uniform group predicates
//     via pos remap; v/probs from global (L1 broadcast), coalesced stores.
// Fallback to the proven V3 single-kernel if ws_size < 7.34 MB.

#define D      64
#define SPAN   32
#define S_SEQ  8192
#define NSPANS 8192                 // (b*h=32) * (8192/32=256)
#define NSCORES (NSPANS * 224)      // 1,835,008
#define NOUT4   (NSPANS * 512)      // spans * 32 pos * 16 float4-chunks

// ---------------- Pass A: scores -> pw[g] = softmax(alpha)[grp] * prob ----
__global__ __launch_bounds__(256) void score_kernel(
    const float* __restrict__ q, const float* __restrict__ k,
    const float* __restrict__ alpha, float* __restrict__ pw) {
    float a0 = alpha[0], a1 = alpha[1], a2 = alpha[2];
    float am = fmaxf(a0, fmaxf(a1, a2));
    float e0 = __expf(a0 - am), e1 = __expf(a1 - am), e2 = __expf(a2 - am);
    float inv = 1.0f / (e0 + e1 + e2);
    const float w0 = e0 * inv, w1 = e1 * inv, w2 = e2 * inv;

    const int stride = gridDim.x * 256;
#pragma unroll 2
    for (int g = blockIdx.x * 256 + threadIdx.x; g < NSCORES; g += stride) {
        const int span = g / 224;              // magic-mul division
        const int t = g - span * 224;
        const int row = t >> 2;                // 0..55
        const int j = t & 3;
        int w, r, win, ii; float wg;
        if (row < 32)      { w = 4;  r = 1; win = row >> 2;        ii = row & 3;        wg = w0; }
        else if (row < 48) { w = 8;  r = 2; win = (row - 32) >> 2; ii = (row - 32) & 3; wg = w1; }
        else               { w = 16; r = 4; win = (row - 48) >> 2; ii = (row - 48) & 3; wg = w2; }
        const long long sb = (long long)span * SPAN;
        const float4* qg = (const float4*)q + (sb + win * w + ii * r) * (D / 4);
        const float4* kg = (const float4*)k + (sb + win * w + j * r) * (D / 4);

        float acc0 = 0.f, acc1 = 0.f, acc2 = 0.f, acc3 = 0.f;
#pragma unroll
        for (int c = 0; c < 16; c += 4) {
            float4 qa = qg[c],     ka = kg[c];
            float4 qb = qg[c + 1], kb = kg[c + 1];
            float4 qc = qg[c + 2], kc = kg[c + 2];
            float4 qd = qg[c + 3], kd = kg[c + 3];
            acc0 += qa.x * ka.x + qa.y * ka.y + qa.z * ka.z + qa.w * ka.w;
            acc1 += qb.x * kb.x + qb.y * kb.y + qb.z * kb.z + qb.w * kb.w;
            acc2 += qc.x * kc.x + qc.y * kc.y + qc.z * kc.z + qc.w * kc.w;
            acc3 += qd.x * kd.x + qd.y * kd.y + qd.z * kd.z + qd.w * kd.w;
        }
        float s = ((acc0 + acc1) + (acc2 + acc3)) * 0.125f;   // d^-0.5
        // 4-lane softmax: quads are lane-aligned (stride % 4 == 0, 224 % 4 == 0)
        float m = fmaxf(s, __shfl_xor(s, 1));
        m = fmaxf(m, __shfl_xor(m, 2));
        float p = __expf(s - m);
        float sum = p + __shfl_xor(p, 1);
        sum += __shfl_xor(sum, 2);
        pw[g] = wg * p / sum;
    }
}

// ---------------- Pass B: out = sum over groups of pw . v ----------------
__global__ __launch_bounds__(256) void pv_kernel(
    const float* __restrict__ v, const float* __restrict__ pw,
    float* __restrict__ out) {
    const int stride = gridDim.x * 256;
#pragma unroll 2
    for (int h = blockIdx.x * 256 + threadIdx.x; h < NOUT4; h += stride) {
        const int span = h >> 9;
        const int rem  = h & 511;
        const int c16  = rem & 15;         // float4 chunk of d (lane-coalesced)
        const int g4   = (rem >> 4) & 3;   // 16-lane group id within wave
        const int b8   = rem >> 6;         // 0..7, wave-uniform
        const int pos  = g4 * 8 + b8;      // pos % 8 == b8 -> predicates uniform
        const int dd   = c16 << 2;
        const long long sb = (long long)span * SPAN;
        const float* vb  = v + sb * D;
        const float* pwb = pw + span * 224;
        float4 acc = make_float4(0.f, 0.f, 0.f, 0.f);

        {   // group 0 (w=4, r=1): rows (pos&~3)+0..3, prob row == pos
            float4 pr = *(const float4*)&pwb[pos * 4];
            const float* vr = vb + (pos & ~3) * D + dd;
            float4 v0 = *(const float4*)(vr);
            float4 v1 = *(const float4*)(vr + D);
            float4 v2 = *(const float4*)(vr + 2 * D);
            float4 v3 = *(const float4*)(vr + 3 * D);
            acc.x += pr.x * v0.x + pr.y * v1.x + pr.z * v2.x + pr.w * v3.x;
            acc.y += pr.x * v0.y + pr.y * v1.y + pr.z * v2.y + pr.w * v3.y;
            acc.z += pr.x * v0.z + pr.y * v1.z + pr.z * v2.z + pr.w * v3.z;
            acc.w += pr.x * v0.w + pr.y * v1.w + pr.z * v2.w + pr.w * v3.w;
        }
        if ((pos & 1) == 0) {  // group 1 (w=8, r=2): wave-uniform predicate
            const int prow = 32 + ((pos >> 3) << 2) + ((pos & 7) >> 1);
            float4 pr = *(const float4*)&pwb[prow * 4];
            const float* vr = vb + (pos & ~7) * D + dd;
            float4 v0 = *(const float4*)(vr);
            float4 v1 = *(const float4*)(vr + 2 * D);
            float4 v2 = *(const float4*)(vr + 4 * D);
            float4 v3 = *(const float4*)(vr + 6 * D);
            acc.x += pr.x * v0.x + pr.y * v1.x + pr.z * v2.x + pr.w * v3.x;
            acc.y += pr.x * v0.y + pr.y * v1.y + pr.z * v2.y + pr.w * v3.y;
            acc.z += pr.x * v0.z + pr.y * v1.z + pr.z * v2.z + pr.w * v3.z;
            acc.w += pr.x * v0.w + pr.y * v1.w + pr.z * v2.w + pr.w * v3.w;
        }
        if ((pos & 3) == 0) {  // group 2 (w=16, r=4): wave-uniform predicate
            const int prow = 48 + ((pos >> 4) << 2) + ((pos & 15) >> 2);
            float4 pr = *(const float4*)&pwb[prow * 4];
            const float* vr = vb + (pos & ~15) * D + dd;
            float4 v0 = *(const float4*)(vr);
            float4 v1 = *(const float4*)(vr + 4 * D);
            float4 v2 = *(const float4*)(vr + 8 * D);
            float4 v3 = *(const float4*)(vr + 12 * D);
            acc.x += pr.x * v0.x + pr.y * v1.x + pr.z * v2.x + pr.w * v3.x;
            acc.y += pr.x * v0.y + pr.y * v1.y + pr.z * v2.y + pr.w * v3.y;
            acc.z += pr.x * v0.z + pr.y * v1.z + pr.z * v2.z + pr.w * v3.z;
            acc.w += pr.x * v0.w + pr.y * v1.w + pr.z * v2.w + pr.w * v3.w;
        }
        *(float4*)&out[(sb + pos) * D + dd] = acc;
    }
}

// ---------------- Fallback: proven V3 single-kernel (93 us) --------------
__device__ __forceinline__ void acc_group_fb(float4& acc, const float* lvs,
                                             const float4 pr, float wg,
                                             int kb, int stride, int dd) {
    float p0 = pr.x * wg, p1 = pr.y * wg, p2 = pr.z * wg, p3 = pr.w * wg;
    const float* vr = &lvs[kb * D + dd];
    float4 v0 = *(const float4*)(vr);
    float4 v1 = *(const float4*)(vr + stride * D);
    float4 v2 = *(const float4*)(vr + 2 * stride * D);
    float4 v3 = *(const float4*)(vr + 3 * stride * D);
    acc.x += p0 * v0.x + p1 * v1.x + p2 * v2.x + p3 * v3.x;
    acc.y += p0 * v0.y + p1 * v1.y + p2 * v2.y + p3 * v3.y;
    acc.z += p0 * v0.z + p1 * v1.z + p2 * v2.z + p3 * v3.z;
    acc.w += p0 * v0.w + p1 * v1.w + p2 * v2.w + p3 * v3.w;
}

__global__ __launch_bounds__(256, 8) void dilated_attn_fallback(
    const float* __restrict__ q, const float* __restrict__ k,
    const float* __restrict__ v, const float* __restrict__ alpha,
    float* __restrict__ out) {
    __shared__ __align__(16) float lv[SPAN * D];
    __shared__ __align__(16) float pl[224];
    const int tid = threadIdx.x;
    const int nspan = S_SEQ / SPAN;
    const int bh = blockIdx.x / nspan;
    const int span = blockIdx.x % nspan;
    const long long rowbase = (long long)bh * S_SEQ + (long long)span * SPAN;
    float a0 = alpha[0], a1 = alpha[1], a2 = alpha[2];
    float am = fmaxf(a0, fmaxf(a1, a2));
    float e0 = __expf(a0 - am), e1 = __expf(a1 - am), e2 = __expf(a2 - am);
    float inv = 1.0f / (e0 + e1 + e2);
    const float w0 = e0 * inv, w1 = e1 * inv, w2 = e2 * inv;
    const int r0 = tid >> 4, r1 = r0 + 16, c4 = tid & 15;
    const float4* v4p = (const float4*)v;
    float4 Rv0 = v4p[(rowbase + r0) * (D / 4) + c4];
    float4 Rv1 = v4p[(rowbase + r1) * (D / 4) + c4];
    if (tid < 224) {
        const int row = tid >> 2, j = tid & 3;
        int w, r, win, ii;
        if (row < 32)      { w = 4;  r = 1; win = row >> 2;        ii = row & 3; }
        else if (row < 48) { w = 8;  r = 2; win = (row - 32) >> 2; ii = (row - 32) & 3; }
        else               { w = 16; r = 4; win = (row - 48) >> 2; ii = (row - 48) & 3; }
        const float4* qg = (const float4*)q + (rowbase + win * w + ii * r) * (D / 4);
        const float4* kg = (const float4*)k + (rowbase + win * w + j * r) * (D / 4);
        float acc4[4] = {0.f, 0.f, 0.f, 0.f};
#pragma unroll
        for (int c = 0; c < 16; ++c) {
            float4 a = qg[c], b = kg[c];
            acc4[c & 3] += a.x * b.x + a.y * b.y + a.z * b.z + a.w * b.w;
        }
        float s = ((acc4[0] + acc4[1]) + (acc4[2] + acc4[3])) * 0.125f;
        float m = fmaxf(s, __shfl_xor(s, 1));
        m = fmaxf(m, __shfl_xor(m, 2));
        float p = __expf(s - m);
        float sum = p + __shfl_xor(p, 1);
        sum += __shfl_xor(sum, 2);
        pl[tid] = p / sum;
    }
    *(float4*)&lv[r0 * D + c4 * 4] = Rv0;
    *(float4*)&lv[r1 * D + c4 * 4] = Rv1;
    __syncthreads();
    const int wv = tid >> 6, lane = tid & 63;
    const int dd = (lane & 15) << 2, psub = lane >> 4;
#pragma unroll
    for (int s2 = 0; s2 < 2; ++s2) {
        const int pos = wv + 16 * s2 + 4 * psub;
        float4 acc = make_float4(0.f, 0.f, 0.f, 0.f);
        { float4 pr = *(const float4*)&pl[pos * 4];
          acc_group_fb(acc, lv, pr, w0, pos & ~3, 1, dd); }
        if ((wv & 1) == 0) {
            const int prow = 32 + ((pos >> 3) << 2) + ((pos & 7) >> 1);
            float4 pr = *(const float4*)&pl[prow * 4];
            acc_group_fb(acc, lv, pr, w1, pos & ~7, 2, dd);
        }
        if (wv == 0) {
            const int prow = 48 + ((pos >> 4) << 2) + ((pos & 15) >> 2);
            float4 pr = *(const float4*)&pl[prow * 4];
            acc_group_fb(acc, lv, pr, w2, pos & ~15, 4, dd);
        }
        *(float4*)&out[(rowbase + pos) * D + dd] = acc;
    }
}

extern "C" void kernel_launch(void* const* d_in, const int* in_sizes, int n_in,
                              void* d_out, int out_size, void* d_ws, size_t ws_size,
                              hipStream_t stream) {
    const float* q = (const float*)d_in[0];
    const float* k = (const float*)d_in[1];
    const float* v = (const float*)d_in[2];
    const float* alpha = (const float*)d_in[3];
    float* out = (float*)d_out;

    if (ws_size >= (size_t)NSCORES * sizeof(float) && d_ws != nullptr) {
        float* pw = (float*)d_ws;
        dim3 block(256);
        hipLaunchKernelGGL(score_kernel, dim3(2048), block, 0, stream,
                           q, k, alpha, pw);
        hipLaunchKernelGGL(pv_kernel, dim3(2048), block, 0, stream,
                           v, pw, out);
    } else {
        const int BH = in_sizes[0] / (S_SEQ * D);             // b*h = 32
        dim3 grid(BH * (S_SEQ / SPAN));                        // 8192 blocks
        dim3 block(256);
        hipLaunchKernelGGL(dilated_attn_fallback, grid, block, 0, stream,
                           q, k, v, alpha, out);
    }
}